// Round 2
// baseline (489.513 us; speedup 1.0000x reference)
//
#include <hip/hip_runtime.h>

typedef __bf16 bf16x8 __attribute__((ext_vector_type(8)));
typedef float  f32x4  __attribute__((ext_vector_type(4)));
typedef unsigned short us8 __attribute__((ext_vector_type(8)));
typedef unsigned short us4 __attribute__((ext_vector_type(4)));

__device__ __forceinline__ float bf2f(unsigned short u) {
    return __builtin_bit_cast(float, (unsigned int)u << 16);
}
__device__ __forceinline__ unsigned short f2bf(float f) {
    return __builtin_bit_cast(unsigned short, (__bf16)f);
}

// ---------------- fused weight prep + cntcur zeroing ----------------
// wt layout per matrix m: [m*32768 .. ]: hiT[128*128], loT[128*128]
__global__ void prep_w4(const float* __restrict__ W0, const float* __restrict__ W1,
                        const float* __restrict__ W2, const float* __restrict__ W3,
                        unsigned short* __restrict__ wt, int* __restrict__ cnt, int N) {
    int i = blockIdx.x * 256 + threadIdx.x;    // 0..65535
    if (i < N) cnt[i] = 0;
    int i2 = i + 65536;
    if (i2 < N) cnt[i2] = 0;
    int m = i >> 14, r = i & 16383;
    const float* W = (m == 0) ? W0 : (m == 1) ? W1 : (m == 2) ? W2 : W3;
    float f = W[r];
    int k = r >> 7, n = r & 127;
    __bf16 h = (__bf16)f;
    __bf16 l = (__bf16)(f - (float)h);
    unsigned short* base = wt + m * 32768;
    base[n * 128 + k]         = __builtin_bit_cast(unsigned short, h);
    base[16384 + n * 128 + k] = __builtin_bit_cast(unsigned short, l);
}

// ---------------- CSR build ----------------
__global__ void count_deg(const int* __restrict__ dst, int* __restrict__ cnt, int E) {
    int e = blockIdx.x * 256 + threadIdx.x;
    if (e < E) atomicAdd(&cnt[dst[e]], 1);
}

// per-1024-block exclusive scan via wave shuffles (2 barriers instead of 20)
__global__ void scanA(const int* __restrict__ cnt, int* __restrict__ rowptr,
                      int* __restrict__ bsum, int N) {
    __shared__ int ws[16];
    int t = threadIdx.x;
    int idx = blockIdx.x * 1024 + t;
    int v = (idx < N) ? cnt[idx] : 0;
    int s = v;
#pragma unroll
    for (int o = 1; o < 64; o <<= 1) {
        int u = __shfl_up(s, o, 64);
        if ((t & 63) >= o) s += u;
    }
    int wid = t >> 6;
    if ((t & 63) == 63) ws[wid] = s;
    __syncthreads();
    if (t < 16) {
        int x = ws[t];
#pragma unroll
        for (int o = 1; o < 16; o <<= 1) {
            int u = __shfl_up(x, o, 64);
            if (t >= o) x += u;
        }
        ws[t] = x;
    }
    __syncthreads();
    int base = (wid > 0) ? ws[wid - 1] : 0;
    int inc = base + s;
    if (idx < N) rowptr[idx] = inc - v;       // exclusive
    if (t == 1023) bsum[blockIdx.x] = inc;    // block total
}

// finalize (absorbs old scanB): per-block prefix of bsum computed in-block.
// q = (b*256)>>10 is constant per block; nb <= 98 < 256 threads.
__global__ void scanC(int* __restrict__ rowptr, const int* __restrict__ bsum,
                      int* __restrict__ cursor, float* __restrict__ dinv,
                      int N, int E) {
    __shared__ int wsum[4];
    __shared__ int sprefix;
    const int b = blockIdx.x;
    const int t = threadIdx.x;
    const int q = (b * 256) >> 10;
    int v = (t < q) ? bsum[t] : 0;
#pragma unroll
    for (int o = 32; o; o >>= 1) v += __shfl_down(v, o, 64);
    if ((t & 63) == 0) wsum[t >> 6] = v;
    __syncthreads();
    if (t == 0) sprefix = wsum[0] + wsum[1] + wsum[2] + wsum[3];
    __syncthreads();
    int i = b * 256 + t;
    if (i < N) {
        int c = cursor[i];
        int a = rowptr[i] + sprefix;
        rowptr[i] = a;
        cursor[i] = a;
        dinv[i] = rsqrtf((float)(c + 1));
    }
    if (i == 0) rowptr[N] = E;
}

// fill edge records (4B: src only), dst-range-partitioned so each range's
// scattered writes stay within ONE XCD's L2 and merge into full lines.
__global__ void fill_csr(const int* __restrict__ src, const int* __restrict__ dst,
                         int* __restrict__ cursor, int* __restrict__ epack,
                         int E, int N) {
    const int range = blockIdx.x & 7;
    const int e = (blockIdx.x >> 3) * 256 + threadIdx.x;
    const int RANGE = (N + 7) >> 3;
    const int lo = range * RANGE;
    const int hi = (lo + RANGE < N) ? lo + RANGE : N;
    if (e < E) {
        int d = dst[e];
        if (d >= lo && d < hi) {
            int p = atomicAdd(&cursor[d], 1);
            epack[p] = src[e];
        }
    }
}

// ---------------- GEMM: C[M,128] = A[M,128](bf16 or f32) @ W[128,128](split hi/lo) ----------------
// Af32 != null : read f32 A, convert in-register (fused x->bf16)
// rowscale != null : C row r scaled by rowscale[r] before store (pre-scaled rows for aggregation)
// mode 0: no bias, write Cb (bf16); mode 1: +bias, PReLU, write Cb; mode 2: +bias, write Cf (f32)
__global__ __launch_bounds__(256) void gemm128s(
    const unsigned short* __restrict__ Ahi, const float* __restrict__ Af32,
    const unsigned short* __restrict__ WhiT, const unsigned short* __restrict__ WloT,
    const float* __restrict__ bias, const float* __restrict__ prelu_a,
    const float* __restrict__ rowscale,
    float* __restrict__ Cf, unsigned short* __restrict__ Cb, int M, int mode)
{
    __shared__ unsigned short sHi[128 * 136];
    __shared__ unsigned short sLo[128 * 136];
    const int tid = threadIdx.x;

    for (int i = tid; i < 2048; i += 256) {
        int row = i >> 4, seg = i & 15;
        *(us8*)(&sHi[row * 136 + seg * 8]) = *(const us8*)(WhiT + row * 128 + seg * 8);
        *(us8*)(&sLo[row * 136 + seg * 8]) = *(const us8*)(WloT + row * 128 + seg * 8);
    }
    __syncthreads();

    const int lane = tid & 63;
    const int wave = tid >> 6;
    const int lc   = lane & 15;
    const int quad = lane >> 4;
    const int rowBlock = blockIdx.x * 128 + wave * 32;

    f32x4 acc[2][8];
    const f32x4 z4 = {0.f, 0.f, 0.f, 0.f};
#pragma unroll
    for (int rs = 0; rs < 2; ++rs)
#pragma unroll
        for (int t = 0; t < 8; ++t) acc[rs][t] = z4;

#pragma unroll
    for (int ks = 0; ks < 4; ++ks) {
        const int kf = ks * 32 + quad * 8;
        bf16x8 a[2];
#pragma unroll
        for (int rs = 0; rs < 2; ++rs) {
            int r = rowBlock + rs * 16 + lc;
            if (r > M - 1) r = M - 1;
            if (Af32) {
                f32x4 p0 = *(const f32x4*)(Af32 + (size_t)r * 128 + kf);
                f32x4 p1 = *(const f32x4*)(Af32 + (size_t)r * 128 + kf + 4);
                us8 u;
#pragma unroll
                for (int j = 0; j < 4; ++j) { u[j] = f2bf(p0[j]); u[j + 4] = f2bf(p1[j]); }
                a[rs] = __builtin_bit_cast(bf16x8, u);
            } else {
                a[rs] = __builtin_bit_cast(bf16x8, *(const us8*)(Ahi + (size_t)r * 128 + kf));
            }
        }
#pragma unroll
        for (int t = 0; t < 8; ++t) {
            bf16x8 bhi = __builtin_bit_cast(bf16x8, *(const us8*)(&sHi[(t * 16 + lc) * 136 + kf]));
            bf16x8 blo = __builtin_bit_cast(bf16x8, *(const us8*)(&sLo[(t * 16 + lc) * 136 + kf]));
#pragma unroll
            for (int rs = 0; rs < 2; ++rs) {
                acc[rs][t] = __builtin_amdgcn_mfma_f32_16x16x32_bf16(a[rs], bhi, acc[rs][t], 0, 0, 0);
                acc[rs][t] = __builtin_amdgcn_mfma_f32_16x16x32_bf16(a[rs], blo, acc[rs][t], 0, 0, 0);
            }
        }
    }

    float rsc[2][4];
#pragma unroll
    for (int rs = 0; rs < 2; ++rs)
#pragma unroll
        for (int i = 0; i < 4; ++i) {
            int r = rowBlock + rs * 16 + quad * 4 + i;
            rsc[rs][i] = (rowscale && r < M) ? rowscale[r] : 1.f;
        }

    float av = (mode == 1) ? prelu_a[0] : 0.f;
#pragma unroll
    for (int t = 0; t < 8; ++t) {
        int gcol = t * 16 + lc;
        float bv = (mode != 0) ? bias[gcol] : 0.f;
#pragma unroll
        for (int rs = 0; rs < 2; ++rs) {
#pragma unroll
            for (int i = 0; i < 4; ++i) {
                int r = rowBlock + rs * 16 + quad * 4 + i;
                if (r < M) {
                    float v = acc[rs][t][i] * rsc[rs][i] + bv;
                    if (mode == 1) v = (v > 0.f) ? v : av * v;
                    if (mode == 2) Cf[(size_t)r * 128 + gcol] = v;
                    else           Cb[(size_t)r * 128 + gcol] = f2bf(v);
                }
            }
        }
    }
}

// ---------------- GCN aggregation: one 64-lane wave per node, 2 features/lane ----------------
// Hs rows are PRE-SCALED by dinv[row]; so
// out[n] = relu( dinv[n] * ( sum_e Hs[src_e] + Hs[n] ) + b )  -- no per-edge weights at all.
__global__ __launch_bounds__(256) void aggregate(
    const unsigned short* __restrict__ Hs, const float* __restrict__ dinv,
    const int* __restrict__ rowptr, const int* __restrict__ epack,
    const float* __restrict__ bias, float* __restrict__ outF,
    unsigned short* __restrict__ outHi, int N)
{
    const int tid = threadIdx.x;
    const int g = tid >> 6;                 // 4 waves per block, 1 node per wave
    const int l = tid & 63;
    const int n = blockIdx.x * 4 + g;
    if (n >= N) return;

    const int beg = rowptr[n], end = rowptr[n + 1];
    const size_t fo = (size_t)l * 2;        // this lane's 2-feature slot

    float a00 = 0.f, a01 = 0.f, a10 = 0.f, a11 = 0.f;
    float a20 = 0.f, a21 = 0.f, a30 = 0.f, a31 = 0.f;

    int i = beg;
    for (; i + 3 < end; i += 4) {
        int s0 = epack[i];
        int s1 = epack[i + 1];
        int s2 = epack[i + 2];
        int s3 = epack[i + 3];
        unsigned int h0 = *(const unsigned int*)(Hs + (size_t)s0 * 128 + fo);
        unsigned int h1 = *(const unsigned int*)(Hs + (size_t)s1 * 128 + fo);
        unsigned int h2 = *(const unsigned int*)(Hs + (size_t)s2 * 128 + fo);
        unsigned int h3 = *(const unsigned int*)(Hs + (size_t)s3 * 128 + fo);
        a00 += bf2f((unsigned short)(h0 & 0xffff)); a01 += bf2f((unsigned short)(h0 >> 16));
        a10 += bf2f((unsigned short)(h1 & 0xffff)); a11 += bf2f((unsigned short)(h1 >> 16));
        a20 += bf2f((unsigned short)(h2 & 0xffff)); a21 += bf2f((unsigned short)(h2 >> 16));
        a30 += bf2f((unsigned short)(h3 & 0xffff)); a31 += bf2f((unsigned short)(h3 >> 16));
    }
    for (; i < end; ++i) {
        int s0 = epack[i];
        unsigned int h0 = *(const unsigned int*)(Hs + (size_t)s0 * 128 + fo);
        a00 += bf2f((unsigned short)(h0 & 0xffff)); a01 += bf2f((unsigned short)(h0 >> 16));
    }

    // self (pre-scaled) + normalize + bias + relu
    unsigned int sh = *(const unsigned int*)(Hs + (size_t)n * 128 + fo);
    float dn = dinv[n];
    float2 b2 = *(const float2*)(bias + l * 2);
    float s0f = ((a00 + a10) + (a20 + a30)) + bf2f((unsigned short)(sh & 0xffff));
    float s1f = ((a01 + a11) + (a21 + a31)) + bf2f((unsigned short)(sh >> 16));
    float v0 = fmaxf(dn * s0f + b2.x, 0.f);
    float v1 = fmaxf(dn * s1f + b2.y, 0.f);
    if (outF) {
        float2 o; o.x = v0; o.y = v1;
        *(float2*)(outF + (size_t)n * 128 + fo) = o;
    }
    unsigned int ob = ((unsigned int)f2bf(v1) << 16) | (unsigned int)f2bf(v0);
    *(unsigned int*)(outHi + (size_t)n * 128 + fo) = ob;
}

// ---------------- launch ----------------
extern "C" void kernel_launch(void* const* d_in, const int* in_sizes, int n_in,
                              void* d_out, int out_size, void* d_ws, size_t ws_size,
                              hipStream_t stream)
{
    const float* x   = (const float*)d_in[0];
    const int*   ei  = (const int*)d_in[1];
    const float* W1  = (const float*)d_in[2];
    const float* b1  = (const float*)d_in[3];
    const float* W2  = (const float*)d_in[4];
    const float* b2  = (const float*)d_in[5];
    const float* Wp1 = (const float*)d_in[6];
    const float* bp1 = (const float*)d_in[7];
    const float* pa  = (const float*)d_in[8];
    const float* Wp2 = (const float*)d_in[9];
    const float* bp2 = (const float*)d_in[10];

    const int N = in_sizes[0] / 128;
    const int E = in_sizes[1] / 2;
    const int* src = ei;
    const int* dst = ei + E;

    float* outF = (float*)d_out;
    float* zbuf = outF;                        // output 0: z
    float* pbuf = outF + (size_t)N * 128;      // output 1: p

    char* w = (char*)d_ws;
    size_t off = 0;
    auto alloc = [&](size_t bytes) {
        void* p = w + off;
        off = (off + bytes + 255) & ~(size_t)255;
        return p;
    };
    unsigned short* S1 = (unsigned short*)alloc((size_t)N * 128 * sizeof(unsigned short));
    unsigned short* S2 = (unsigned short*)alloc((size_t)N * 128 * sizeof(unsigned short));
    float* dinv   = (float*)alloc((size_t)N * sizeof(float));
    int*   rowptr = (int*)alloc((size_t)(N + 1) * sizeof(int));
    int*   cntcur = (int*)alloc((size_t)N * sizeof(int));
    int*   epack  = (int*)alloc((size_t)E * sizeof(int));
    int*   bsum   = (int*)alloc(1024);
    unsigned short* wt = (unsigned short*)alloc((size_t)4 * 2 * 128 * 128 * sizeof(unsigned short));
    (void)ws_size; (void)n_in; (void)out_size;

    auto hiP = [&](int m) { return wt + (size_t)m * 32768; };
    auto loP = [&](int m) { return wt + (size_t)m * 32768 + 16384; };

    // weight conversion + cntcur zeroing (fused)
    hipLaunchKernelGGL(prep_w4, dim3(256), dim3(256), 0, stream, W1, W2, Wp1, Wp2, wt, cntcur, N);

    // CSR by dst
    const int nb = (N + 1023) >> 10;
    hipLaunchKernelGGL(count_deg, dim3((E + 255) / 256), dim3(256), 0, stream, dst, cntcur, E);
    hipLaunchKernelGGL(scanA,     dim3(nb), dim3(1024), 0, stream, cntcur, rowptr, bsum, N);
    hipLaunchKernelGGL(scanC,     dim3((N + 255) / 256), dim3(256), 0, stream, rowptr, bsum, cntcur, dinv, N, E);
    hipLaunchKernelGGL(fill_csr,  dim3(8 * ((E + 255) / 256)), dim3(256), 0, stream,
                       src, dst, cntcur, epack, E, N);

    const int gb = (N + 127) / 128;
    const int ab = (N + 3) / 4;
    // conv1: h1s = (x@W1)*dinv -> S2 (reads f32 x directly) ; z1 = relu(dinv*(agg+self)+b1) -> S1
    hipLaunchKernelGGL(gemm128s, dim3(gb), dim3(256), 0, stream,
                       (const unsigned short*)nullptr, x, hiP(0), loP(0),
                       (const float*)nullptr, (const float*)nullptr, dinv,
                       (float*)nullptr, S2, N, 0);
    hipLaunchKernelGGL(aggregate, dim3(ab), dim3(256), 0, stream, S2, dinv, rowptr, epack,
                       b1, (float*)nullptr, S1, N);
    // conv2: h2s = (z1@W2)*dinv -> S2 ; z = relu(dinv*(agg+self)+b2) -> zbuf(f32) + S1(bf16)
    hipLaunchKernelGGL(gemm128s, dim3(gb), dim3(256), 0, stream,
                       S1, (const float*)nullptr, hiP(1), loP(1),
                       (const float*)nullptr, (const float*)nullptr, dinv,
                       (float*)nullptr, S2, N, 0);
    hipLaunchKernelGGL(aggregate, dim3(ab), dim3(256), 0, stream, S2, dinv, rowptr, epack,
                       b2, zbuf, S1, N);
    // projection: h = prelu(z@Wp1+bp1) -> S2 ; p = h@Wp2+bp2 -> pbuf(f32)
    hipLaunchKernelGGL(gemm128s, dim3(gb), dim3(256), 0, stream,
                       S1, (const float*)nullptr, hiP(2), loP(2),
                       bp1, pa, (const float*)nullptr,
                       (float*)nullptr, S2, N, 1);
    hipLaunchKernelGGL(gemm128s, dim3(gb), dim3(256), 0, stream,
                       S2, (const float*)nullptr, hiP(3), loP(3),
                       bp2, (const float*)nullptr, (const float*)nullptr,
                       pbuf, (unsigned short*)nullptr, N, 2);
}

// Round 3
// 488.741 us; speedup vs baseline: 1.0016x; 1.0016x over previous
//
#include <hip/hip_runtime.h>

typedef __bf16 bf16x8 __attribute__((ext_vector_type(8)));
typedef float  f32x4  __attribute__((ext_vector_type(4)));
typedef unsigned short us8 __attribute__((ext_vector_type(8)));
typedef unsigned short us4 __attribute__((ext_vector_type(4)));

__device__ __forceinline__ float bf2f(unsigned short u) {
    return __builtin_bit_cast(float, (unsigned int)u << 16);
}
__device__ __forceinline__ unsigned short f2bf(float f) {
    return __builtin_bit_cast(unsigned short, (__bf16)f);
}

// ---------------- fused weight prep + cntcur zeroing ----------------
// wt layout per matrix m: [m*32768 .. ]: hiT[128*128], loT[128*128]
__global__ void prep_w4(const float* __restrict__ W0, const float* __restrict__ W1,
                        const float* __restrict__ W2, const float* __restrict__ W3,
                        unsigned short* __restrict__ wt, int* __restrict__ cnt, int N) {
    int i = blockIdx.x * 256 + threadIdx.x;    // 0..65535
    if (i < N) cnt[i] = 0;
    int i2 = i + 65536;
    if (i2 < N) cnt[i2] = 0;
    int m = i >> 14, r = i & 16383;
    const float* W = (m == 0) ? W0 : (m == 1) ? W1 : (m == 2) ? W2 : W3;
    float f = W[r];
    int k = r >> 7, n = r & 127;
    __bf16 h = (__bf16)f;
    __bf16 l = (__bf16)(f - (float)h);
    unsigned short* base = wt + m * 32768;
    base[n * 128 + k]         = __builtin_bit_cast(unsigned short, h);
    base[16384 + n * 128 + k] = __builtin_bit_cast(unsigned short, l);
}

// ---------------- CSR build ----------------
__global__ void count_deg(const int* __restrict__ dst, int* __restrict__ cnt, int E) {
    int e = blockIdx.x * 256 + threadIdx.x;
    if (e < E) atomicAdd(&cnt[dst[e]], 1);
}

// per-1024-block exclusive scan via wave shuffles
__global__ void scanA(const int* __restrict__ cnt, int* __restrict__ rowptr,
                      int* __restrict__ bsum, int N) {
    __shared__ int ws[16];
    int t = threadIdx.x;
    int idx = blockIdx.x * 1024 + t;
    int v = (idx < N) ? cnt[idx] : 0;
    int s = v;
#pragma unroll
    for (int o = 1; o < 64; o <<= 1) {
        int u = __shfl_up(s, o, 64);
        if ((t & 63) >= o) s += u;
    }
    int wid = t >> 6;
    if ((t & 63) == 63) ws[wid] = s;
    __syncthreads();
    if (t < 16) {
        int x = ws[t];
#pragma unroll
        for (int o = 1; o < 16; o <<= 1) {
            int u = __shfl_up(x, o, 64);
            if (t >= o) x += u;
        }
        ws[t] = x;
    }
    __syncthreads();
    int base = (wid > 0) ? ws[wid - 1] : 0;
    int inc = base + s;
    if (idx < N) rowptr[idx] = inc - v;       // exclusive
    if (t == 1023) bsum[blockIdx.x] = inc;    // block total
}

// finalize: per-block prefix of bsum computed in-block (nb <= 98 < 256)
__global__ void scanC(int* __restrict__ rowptr, const int* __restrict__ bsum,
                      int* __restrict__ cursor, float* __restrict__ dinv,
                      int N, int E) {
    __shared__ int wsum[4];
    __shared__ int sprefix;
    const int b = blockIdx.x;
    const int t = threadIdx.x;
    const int q = (b * 256) >> 10;
    int v = (t < q) ? bsum[t] : 0;
#pragma unroll
    for (int o = 32; o; o >>= 1) v += __shfl_down(v, o, 64);
    if ((t & 63) == 0) wsum[t >> 6] = v;
    __syncthreads();
    if (t == 0) sprefix = wsum[0] + wsum[1] + wsum[2] + wsum[3];
    __syncthreads();
    int i = b * 256 + t;
    if (i < N) {
        int c = cursor[i];
        int a = rowptr[i] + sprefix;
        rowptr[i] = a;
        cursor[i] = a;
        dinv[i] = rsqrtf((float)(c + 1));
    }
    if (i == 0) rowptr[N] = E;
}

// fill edge records (4B: src only), dst-range-partitioned so each range's
// scattered writes stay within ONE XCD's L2 and merge into full lines.
__global__ void fill_csr(const int* __restrict__ src, const int* __restrict__ dst,
                         int* __restrict__ cursor, int* __restrict__ epack,
                         int E, int N) {
    const int range = blockIdx.x & 7;
    const int e = (blockIdx.x >> 3) * 256 + threadIdx.x;
    const int RANGE = (N + 7) >> 3;
    const int lo = range * RANGE;
    const int hi = (lo + RANGE < N) ? lo + RANGE : N;
    if (e < E) {
        int d = dst[e];
        if (d >= lo && d < hi) {
            int p = atomicAdd(&cursor[d], 1);
            epack[p] = src[e];
        }
    }
}

// ---------------- GEMM: C[M,128] = A[M,128](bf16 or f32) @ W[128,128](split hi/lo) ----------------
// Af32 != null : read f32 A, convert in-register (fused x->bf16)
// rowscale != null : C row r scaled by rowscale[r] before store
__global__ __launch_bounds__(256) void gemm128s(
    const unsigned short* __restrict__ Ahi, const float* __restrict__ Af32,
    const unsigned short* __restrict__ WhiT, const unsigned short* __restrict__ WloT,
    const float* __restrict__ rowscale, unsigned short* __restrict__ Cb, int M)
{
    __shared__ unsigned short sHi[128 * 136];
    __shared__ unsigned short sLo[128 * 136];
    const int tid = threadIdx.x;

    for (int i = tid; i < 2048; i += 256) {
        int row = i >> 4, seg = i & 15;
        *(us8*)(&sHi[row * 136 + seg * 8]) = *(const us8*)(WhiT + row * 128 + seg * 8);
        *(us8*)(&sLo[row * 136 + seg * 8]) = *(const us8*)(WloT + row * 128 + seg * 8);
    }
    __syncthreads();

    const int lane = tid & 63;
    const int wave = tid >> 6;
    const int lc   = lane & 15;
    const int quad = lane >> 4;
    const int rowBlock = blockIdx.x * 128 + wave * 32;

    f32x4 acc[2][8];
    const f32x4 z4 = {0.f, 0.f, 0.f, 0.f};
#pragma unroll
    for (int rs = 0; rs < 2; ++rs)
#pragma unroll
        for (int t = 0; t < 8; ++t) acc[rs][t] = z4;

#pragma unroll
    for (int ks = 0; ks < 4; ++ks) {
        const int kf = ks * 32 + quad * 8;
        bf16x8 a[2];
#pragma unroll
        for (int rs = 0; rs < 2; ++rs) {
            int r = rowBlock + rs * 16 + lc;
            if (r > M - 1) r = M - 1;
            if (Af32) {
                f32x4 p0 = *(const f32x4*)(Af32 + (size_t)r * 128 + kf);
                f32x4 p1 = *(const f32x4*)(Af32 + (size_t)r * 128 + kf + 4);
                us8 u;
#pragma unroll
                for (int j = 0; j < 4; ++j) { u[j] = f2bf(p0[j]); u[j + 4] = f2bf(p1[j]); }
                a[rs] = __builtin_bit_cast(bf16x8, u);
            } else {
                a[rs] = __builtin_bit_cast(bf16x8, *(const us8*)(Ahi + (size_t)r * 128 + kf));
            }
        }
#pragma unroll
        for (int t = 0; t < 8; ++t) {
            bf16x8 bhi = __builtin_bit_cast(bf16x8, *(const us8*)(&sHi[(t * 16 + lc) * 136 + kf]));
            bf16x8 blo = __builtin_bit_cast(bf16x8, *(const us8*)(&sLo[(t * 16 + lc) * 136 + kf]));
#pragma unroll
            for (int rs = 0; rs < 2; ++rs) {
                acc[rs][t] = __builtin_amdgcn_mfma_f32_16x16x32_bf16(a[rs], bhi, acc[rs][t], 0, 0, 0);
                acc[rs][t] = __builtin_amdgcn_mfma_f32_16x16x32_bf16(a[rs], blo, acc[rs][t], 0, 0, 0);
            }
        }
    }

    float rsc[2][4];
#pragma unroll
    for (int rs = 0; rs < 2; ++rs)
#pragma unroll
        for (int i = 0; i < 4; ++i) {
            int r = rowBlock + rs * 16 + quad * 4 + i;
            rsc[rs][i] = (rowscale && r < M) ? rowscale[r] : 1.f;
        }

#pragma unroll
    for (int t = 0; t < 8; ++t) {
        int gcol = t * 16 + lc;
#pragma unroll
        for (int rs = 0; rs < 2; ++rs) {
#pragma unroll
            for (int i = 0; i < 4; ++i) {
                int r = rowBlock + rs * 16 + quad * 4 + i;
                if (r < M) Cb[(size_t)r * 128 + gcol] = f2bf(acc[rs][t][i] * rsc[rs][i]);
            }
        }
    }
}

// ---------------- fused projection: p = prelu(z@Wp1+b1)@Wp2+b2 ----------------
// Each wave's gemm1 D-fragments (32 rows x 128 cols) ARE gemm2's A-rows: pass them
// through a private per-wave LDS slice (132-padded). B-fragments for both GEMMs
// read directly from global (weights are L2-resident; all waves share addresses).
__global__ __launch_bounds__(256) void proj_fused(
    const unsigned short* __restrict__ A,
    const unsigned short* __restrict__ W1hiT, const unsigned short* __restrict__ W1loT,
    const unsigned short* __restrict__ W2hiT, const unsigned short* __restrict__ W2loT,
    const float* __restrict__ b1, const float* __restrict__ prelu_a,
    const float* __restrict__ b2, float* __restrict__ P, int M)
{
    __shared__ unsigned short hLds[4][32 * 132];
    const int tid  = threadIdx.x;
    const int lane = tid & 63;
    const int wave = tid >> 6;
    const int lc   = lane & 15;
    const int quad = lane >> 4;
    const int rowBlock = blockIdx.x * 128 + wave * 32;

    f32x4 acc[2][8];
    const f32x4 z4 = {0.f, 0.f, 0.f, 0.f};
#pragma unroll
    for (int rs = 0; rs < 2; ++rs)
#pragma unroll
        for (int t = 0; t < 8; ++t) acc[rs][t] = z4;

    // ---- gemm1: z @ Wp1 ----
#pragma unroll
    for (int ks = 0; ks < 4; ++ks) {
        const int kf = ks * 32 + quad * 8;
        bf16x8 a[2];
#pragma unroll
        for (int rs = 0; rs < 2; ++rs) {
            int r = rowBlock + rs * 16 + lc;
            if (r > M - 1) r = M - 1;
            a[rs] = __builtin_bit_cast(bf16x8, *(const us8*)(A + (size_t)r * 128 + kf));
        }
#pragma unroll
        for (int t = 0; t < 8; ++t) {
            bf16x8 bhi = __builtin_bit_cast(bf16x8, *(const us8*)(W1hiT + (t * 16 + lc) * 128 + kf));
            bf16x8 blo = __builtin_bit_cast(bf16x8, *(const us8*)(W1loT + (t * 16 + lc) * 128 + kf));
#pragma unroll
            for (int rs = 0; rs < 2; ++rs) {
                acc[rs][t] = __builtin_amdgcn_mfma_f32_16x16x32_bf16(a[rs], bhi, acc[rs][t], 0, 0, 0);
                acc[rs][t] = __builtin_amdgcn_mfma_f32_16x16x32_bf16(a[rs], blo, acc[rs][t], 0, 0, 0);
            }
        }
    }

    // bias + PReLU, scatter wave tile into private LDS slice (D-layout)
    float av = prelu_a[0];
#pragma unroll
    for (int t = 0; t < 8; ++t) {
        float bv = b1[t * 16 + lc];
#pragma unroll
        for (int rs = 0; rs < 2; ++rs) {
#pragma unroll
            for (int i = 0; i < 4; ++i) {
                int rl = rs * 16 + quad * 4 + i;
                float v = acc[rs][t][i] + bv;
                v = (v > 0.f) ? v : av * v;
                hLds[wave][rl * 132 + t * 16 + lc] = f2bf(v);
            }
        }
    }
    __syncthreads();

    // ---- gemm2: h @ Wp2 ----
    f32x4 acc2[2][8];
#pragma unroll
    for (int rs = 0; rs < 2; ++rs)
#pragma unroll
        for (int t = 0; t < 8; ++t) acc2[rs][t] = z4;

#pragma unroll
    for (int ks = 0; ks < 4; ++ks) {
        const int kf = ks * 32 + quad * 8;
        bf16x8 a[2];
#pragma unroll
        for (int rs = 0; rs < 2; ++rs)
            a[rs] = __builtin_bit_cast(bf16x8, *(const us8*)(&hLds[wave][(rs * 16 + lc) * 132 + kf]));
#pragma unroll
        for (int t = 0; t < 8; ++t) {
            bf16x8 bhi = __builtin_bit_cast(bf16x8, *(const us8*)(W2hiT + (t * 16 + lc) * 128 + kf));
            bf16x8 blo = __builtin_bit_cast(bf16x8, *(const us8*)(W2loT + (t * 16 + lc) * 128 + kf));
#pragma unroll
            for (int rs = 0; rs < 2; ++rs) {
                acc2[rs][t] = __builtin_amdgcn_mfma_f32_16x16x32_bf16(a[rs], bhi, acc2[rs][t], 0, 0, 0);
                acc2[rs][t] = __builtin_amdgcn_mfma_f32_16x16x32_bf16(a[rs], blo, acc2[rs][t], 0, 0, 0);
            }
        }
    }

#pragma unroll
    for (int t = 0; t < 8; ++t) {
        int gcol = t * 16 + lc;
        float bv = b2[gcol];
#pragma unroll
        for (int rs = 0; rs < 2; ++rs) {
#pragma unroll
            for (int i = 0; i < 4; ++i) {
                int r = rowBlock + rs * 16 + quad * 4 + i;
                if (r < M) P[(size_t)r * 128 + gcol] = acc2[rs][t][i] + bv;
            }
        }
    }
}

// ---------------- GCN aggregation: 32-lane group per node (2 nodes/wave), 4 feats/lane ----------------
// Hs rows PRE-SCALED by dinv[row]: out[n] = relu( dinv[n]*(sum_e Hs[src_e] + Hs[n]) + b )
__global__ __launch_bounds__(256) void aggregate(
    const unsigned short* __restrict__ Hs, const float* __restrict__ dinv,
    const int* __restrict__ rowptr, const int* __restrict__ epack,
    const float* __restrict__ bias, float* __restrict__ outF,
    unsigned short* __restrict__ outHi, int N)
{
    const int tid = threadIdx.x;
    const int g = tid >> 5;                 // 8 groups of 32 lanes
    const int l = tid & 31;
    const int n = blockIdx.x * 8 + g;
    if (n >= N) return;

    const int beg = rowptr[n], end = rowptr[n + 1];
    const size_t fo = (size_t)l * 4;        // this lane's 4-feature slot

    f32x4 a0 = {0.f, 0.f, 0.f, 0.f};
    f32x4 a1 = a0, a2 = a0, a3 = a0;

    int i = beg;
    for (; i + 3 < end; i += 4) {
        int s0 = epack[i];
        int s1 = epack[i + 1];
        int s2 = epack[i + 2];
        int s3 = epack[i + 3];
        us4 h0 = *(const us4*)(Hs + (size_t)s0 * 128 + fo);
        us4 h1 = *(const us4*)(Hs + (size_t)s1 * 128 + fo);
        us4 h2 = *(const us4*)(Hs + (size_t)s2 * 128 + fo);
        us4 h3 = *(const us4*)(Hs + (size_t)s3 * 128 + fo);
#pragma unroll
        for (int j = 0; j < 4; ++j) a0[j] += bf2f(h0[j]);
#pragma unroll
        for (int j = 0; j < 4; ++j) a1[j] += bf2f(h1[j]);
#pragma unroll
        for (int j = 0; j < 4; ++j) a2[j] += bf2f(h2[j]);
#pragma unroll
        for (int j = 0; j < 4; ++j) a3[j] += bf2f(h3[j]);
    }
    for (; i < end; ++i) {
        int s0 = epack[i];
        us4 h0 = *(const us4*)(Hs + (size_t)s0 * 128 + fo);
#pragma unroll
        for (int j = 0; j < 4; ++j) a0[j] += bf2f(h0[j]);
    }

    // self (pre-scaled) + normalize + bias + relu
    us4 sh = *(const us4*)(Hs + (size_t)n * 128 + fo);
    float dn = dinv[n];
    f32x4 b4 = *(const f32x4*)(bias + l * 4);
    f32x4 sum = (a0 + a1) + (a2 + a3);
    f32x4 v;
    us4 ob;
#pragma unroll
    for (int j = 0; j < 4; ++j) {
        v[j] = fmaxf(dn * (sum[j] + bf2f(sh[j])) + b4[j], 0.f);
        ob[j] = f2bf(v[j]);
    }
    if (outF) *(f32x4*)(outF + (size_t)n * 128 + fo) = v;
    *(us4*)(outHi + (size_t)n * 128 + fo) = ob;
}

// ---------------- launch ----------------
extern "C" void kernel_launch(void* const* d_in, const int* in_sizes, int n_in,
                              void* d_out, int out_size, void* d_ws, size_t ws_size,
                              hipStream_t stream)
{
    const float* x   = (const float*)d_in[0];
    const int*   ei  = (const int*)d_in[1];
    const float* W1  = (const float*)d_in[2];
    const float* b1  = (const float*)d_in[3];
    const float* W2  = (const float*)d_in[4];
    const float* b2  = (const float*)d_in[5];
    const float* Wp1 = (const float*)d_in[6];
    const float* bp1 = (const float*)d_in[7];
    const float* pa  = (const float*)d_in[8];
    const float* Wp2 = (const float*)d_in[9];
    const float* bp2 = (const float*)d_in[10];

    const int N = in_sizes[0] / 128;
    const int E = in_sizes[1] / 2;
    const int* src = ei;
    const int* dst = ei + E;

    float* outF = (float*)d_out;
    float* zbuf = outF;                        // output 0: z
    float* pbuf = outF + (size_t)N * 128;      // output 1: p

    char* w = (char*)d_ws;
    size_t off = 0;
    auto alloc = [&](size_t bytes) {
        void* p = w + off;
        off = (off + bytes + 255) & ~(size_t)255;
        return p;
    };
    unsigned short* S1 = (unsigned short*)alloc((size_t)N * 128 * sizeof(unsigned short));
    unsigned short* S2 = (unsigned short*)alloc((size_t)N * 128 * sizeof(unsigned short));
    float* dinv   = (float*)alloc((size_t)N * sizeof(float));
    int*   rowptr = (int*)alloc((size_t)(N + 1) * sizeof(int));
    int*   cntcur = (int*)alloc((size_t)N * sizeof(int));
    int*   epack  = (int*)alloc((size_t)E * sizeof(int));
    int*   bsum   = (int*)alloc(1024);
    unsigned short* wt = (unsigned short*)alloc((size_t)4 * 2 * 128 * 128 * sizeof(unsigned short));
    (void)ws_size; (void)n_in; (void)out_size;

    auto hiP = [&](int m) { return wt + (size_t)m * 32768; };
    auto loP = [&](int m) { return wt + (size_t)m * 32768 + 16384; };

    // weight conversion + cntcur zeroing (fused)
    hipLaunchKernelGGL(prep_w4, dim3(256), dim3(256), 0, stream, W1, W2, Wp1, Wp2, wt, cntcur, N);

    // CSR by dst
    const int nb = (N + 1023) >> 10;
    hipLaunchKernelGGL(count_deg, dim3((E + 255) / 256), dim3(256), 0, stream, dst, cntcur, E);
    hipLaunchKernelGGL(scanA,     dim3(nb), dim3(1024), 0, stream, cntcur, rowptr, bsum, N);
    hipLaunchKernelGGL(scanC,     dim3((N + 255) / 256), dim3(256), 0, stream, rowptr, bsum, cntcur, dinv, N, E);
    hipLaunchKernelGGL(fill_csr,  dim3(8 * ((E + 255) / 256)), dim3(256), 0, stream,
                       src, dst, cntcur, epack, E, N);

    const int gb = (N + 127) / 128;
    const int ab = (N + 7) / 8;
    // conv1: h1s = (x@W1)*dinv -> S2 (reads f32 x directly) ; z1 = relu(dinv*(agg+self)+b1) -> S1
    hipLaunchKernelGGL(gemm128s, dim3(gb), dim3(256), 0, stream,
                       (const unsigned short*)nullptr, x, hiP(0), loP(0), dinv, S2, N);
    hipLaunchKernelGGL(aggregate, dim3(ab), dim3(256), 0, stream, S2, dinv, rowptr, epack,
                       b1, (float*)nullptr, S1, N);
    // conv2: h2s = (z1@W2)*dinv -> S2 ; z = relu(dinv*(agg+self)+b2) -> zbuf(f32) + S1(bf16)
    hipLaunchKernelGGL(gemm128s, dim3(gb), dim3(256), 0, stream,
                       S1, (const float*)nullptr, hiP(1), loP(1), dinv, S2, N);
    hipLaunchKernelGGL(aggregate, dim3(ab), dim3(256), 0, stream, S2, dinv, rowptr, epack,
                       b2, zbuf, S1, N);
    // fused projection: p = prelu(z@Wp1+bp1)@Wp2+bp2 -> pbuf
    hipLaunchKernelGGL(proj_fused, dim3(gb), dim3(256), 0, stream,
                       S1, hiP(2), loP(2), hiP(3), loP(3), bp1, pa, bp2, pbuf, N);
}

// Round 4
// 475.667 us; speedup vs baseline: 1.0291x; 1.0275x over previous
//
#include <hip/hip_runtime.h>

typedef __bf16 bf16x8 __attribute__((ext_vector_type(8)));
typedef float  f32x4  __attribute__((ext_vector_type(4)));
typedef unsigned short us8 __attribute__((ext_vector_type(8)));
typedef unsigned short us4 __attribute__((ext_vector_type(4)));

__device__ __forceinline__ float bf2f(unsigned short u) {
    return __builtin_bit_cast(float, (unsigned int)u << 16);
}
__device__ __forceinline__ unsigned short f2bf(float f) {
    return __builtin_bit_cast(unsigned short, (__bf16)f);
}

// ---------------- fused weight prep + cntcur zeroing ----------------
// wt layout per matrix m: [m*32768 .. ]: hiT[128*128], loT[128*128]
__global__ void prep_w4(const float* __restrict__ W0, const float* __restrict__ W1,
                        const float* __restrict__ W2, const float* __restrict__ W3,
                        unsigned short* __restrict__ wt, int* __restrict__ cnt, int N) {
    int i = blockIdx.x * 256 + threadIdx.x;    // 0..65535
    if (i < N) cnt[i] = 0;
    int i2 = i + 65536;
    if (i2 < N) cnt[i2] = 0;
    int m = i >> 14, r = i & 16383;
    const float* W = (m == 0) ? W0 : (m == 1) ? W1 : (m == 2) ? W2 : W3;
    float f = W[r];
    int k = r >> 7, n = r & 127;
    __bf16 h = (__bf16)f;
    __bf16 l = (__bf16)(f - (float)h);
    unsigned short* base = wt + m * 32768;
    base[n * 128 + k]         = __builtin_bit_cast(unsigned short, h);
    base[16384 + n * 128 + k] = __builtin_bit_cast(unsigned short, l);
}

// ---------------- CSR build ----------------
__global__ void count_deg(const int* __restrict__ dst, int* __restrict__ cnt, int E) {
    int e = blockIdx.x * 256 + threadIdx.x;
    if (e < E) atomicAdd(&cnt[dst[e]], 1);
}

// per-1024-block exclusive scan via wave shuffles
__global__ void scanA(const int* __restrict__ cnt, int* __restrict__ rowptr,
                      int* __restrict__ bsum, int N) {
    __shared__ int ws[16];
    int t = threadIdx.x;
    int idx = blockIdx.x * 1024 + t;
    int v = (idx < N) ? cnt[idx] : 0;
    int s = v;
#pragma unroll
    for (int o = 1; o < 64; o <<= 1) {
        int u = __shfl_up(s, o, 64);
        if ((t & 63) >= o) s += u;
    }
    int wid = t >> 6;
    if ((t & 63) == 63) ws[wid] = s;
    __syncthreads();
    if (t < 16) {
        int x = ws[t];
#pragma unroll
        for (int o = 1; o < 16; o <<= 1) {
            int u = __shfl_up(x, o, 64);
            if (t >= o) x += u;
        }
        ws[t] = x;
    }
    __syncthreads();
    int base = (wid > 0) ? ws[wid - 1] : 0;
    int inc = base + s;
    if (idx < N) rowptr[idx] = inc - v;       // exclusive
    if (t == 1023) bsum[blockIdx.x] = inc;    // block total
}

// finalize: per-block prefix of bsum computed in-block (nb <= 98 < 256)
__global__ void scanC(int* __restrict__ rowptr, const int* __restrict__ bsum,
                      int* __restrict__ cursor, float* __restrict__ dinv,
                      int N, int E) {
    __shared__ int wsum[4];
    __shared__ int sprefix;
    const int b = blockIdx.x;
    const int t = threadIdx.x;
    const int q = (b * 256) >> 10;
    int v = (t < q) ? bsum[t] : 0;
#pragma unroll
    for (int o = 32; o; o >>= 1) v += __shfl_down(v, o, 64);
    if ((t & 63) == 0) wsum[t >> 6] = v;
    __syncthreads();
    if (t == 0) sprefix = wsum[0] + wsum[1] + wsum[2] + wsum[3];
    __syncthreads();
    int i = b * 256 + t;
    if (i < N) {
        int c = cursor[i];
        int a = rowptr[i] + sprefix;
        rowptr[i] = a;
        cursor[i] = a;
        dinv[i] = rsqrtf((float)(c + 1));
    }
    if (i == 0) rowptr[N] = E;
}

// fill edge records (4B: src only), dst-range-partitioned so each range's
// scattered writes stay within ONE XCD's L2 and merge into full lines.
__global__ void fill_csr(const int* __restrict__ src, const int* __restrict__ dst,
                         int* __restrict__ cursor, int* __restrict__ epack,
                         int E, int N) {
    const int range = blockIdx.x & 7;
    const int e = (blockIdx.x >> 3) * 256 + threadIdx.x;
    const int RANGE = (N + 7) >> 3;
    const int lo = range * RANGE;
    const int hi = (lo + RANGE < N) ? lo + RANGE : N;
    if (e < E) {
        int d = dst[e];
        if (d >= lo && d < hi) {
            int p = atomicAdd(&cursor[d], 1);
            epack[p] = src[e];
        }
    }
}

// ---------------- GEMM: C[M,128] = A[M,128](bf16 or f32) @ W[128,128](split hi/lo) ----------------
// Af32 != null : read f32 A, convert in-register (fused x->bf16)
// rowscale != null : C row r scaled by rowscale[r] before store
// mode 0: no bias, write Cb (bf16); mode 1: +bias, PReLU, write Cb; mode 2: +bias, write Cf (f32)
__global__ __launch_bounds__(256) void gemm128s(
    const unsigned short* __restrict__ Ahi, const float* __restrict__ Af32,
    const unsigned short* __restrict__ WhiT, const unsigned short* __restrict__ WloT,
    const float* __restrict__ bias, const float* __restrict__ prelu_a,
    const float* __restrict__ rowscale,
    float* __restrict__ Cf, unsigned short* __restrict__ Cb, int M, int mode)
{
    __shared__ unsigned short sHi[128 * 136];
    __shared__ unsigned short sLo[128 * 136];
    const int tid = threadIdx.x;

    for (int i = tid; i < 2048; i += 256) {
        int row = i >> 4, seg = i & 15;
        *(us8*)(&sHi[row * 136 + seg * 8]) = *(const us8*)(WhiT + row * 128 + seg * 8);
        *(us8*)(&sLo[row * 136 + seg * 8]) = *(const us8*)(WloT + row * 128 + seg * 8);
    }
    __syncthreads();

    const int lane = tid & 63;
    const int wave = tid >> 6;
    const int lc   = lane & 15;
    const int quad = lane >> 4;
    const int rowBlock = blockIdx.x * 128 + wave * 32;

    f32x4 acc[2][8];
    const f32x4 z4 = {0.f, 0.f, 0.f, 0.f};
#pragma unroll
    for (int rs = 0; rs < 2; ++rs)
#pragma unroll
        for (int t = 0; t < 8; ++t) acc[rs][t] = z4;

#pragma unroll
    for (int ks = 0; ks < 4; ++ks) {
        const int kf = ks * 32 + quad * 8;
        bf16x8 a[2];
#pragma unroll
        for (int rs = 0; rs < 2; ++rs) {
            int r = rowBlock + rs * 16 + lc;
            if (r > M - 1) r = M - 1;
            if (Af32) {
                f32x4 p0 = *(const f32x4*)(Af32 + (size_t)r * 128 + kf);
                f32x4 p1 = *(const f32x4*)(Af32 + (size_t)r * 128 + kf + 4);
                us8 u;
#pragma unroll
                for (int j = 0; j < 4; ++j) { u[j] = f2bf(p0[j]); u[j + 4] = f2bf(p1[j]); }
                a[rs] = __builtin_bit_cast(bf16x8, u);
            } else {
                a[rs] = __builtin_bit_cast(bf16x8, *(const us8*)(Ahi + (size_t)r * 128 + kf));
            }
        }
#pragma unroll
        for (int t = 0; t < 8; ++t) {
            bf16x8 bhi = __builtin_bit_cast(bf16x8, *(const us8*)(&sHi[(t * 16 + lc) * 136 + kf]));
            bf16x8 blo = __builtin_bit_cast(bf16x8, *(const us8*)(&sLo[(t * 16 + lc) * 136 + kf]));
#pragma unroll
            for (int rs = 0; rs < 2; ++rs) {
                acc[rs][t] = __builtin_amdgcn_mfma_f32_16x16x32_bf16(a[rs], bhi, acc[rs][t], 0, 0, 0);
                acc[rs][t] = __builtin_amdgcn_mfma_f32_16x16x32_bf16(a[rs], blo, acc[rs][t], 0, 0, 0);
            }
        }
    }

    float rsc[2][4];
#pragma unroll
    for (int rs = 0; rs < 2; ++rs)
#pragma unroll
        for (int i = 0; i < 4; ++i) {
            int r = rowBlock + rs * 16 + quad * 4 + i;
            rsc[rs][i] = (rowscale && r < M) ? rowscale[r] : 1.f;
        }

    float av = (mode == 1) ? prelu_a[0] : 0.f;
#pragma unroll
    for (int t = 0; t < 8; ++t) {
        int gcol = t * 16 + lc;
        float bv = (mode != 0) ? bias[gcol] : 0.f;
#pragma unroll
        for (int rs = 0; rs < 2; ++rs) {
#pragma unroll
            for (int i = 0; i < 4; ++i) {
                int r = rowBlock + rs * 16 + quad * 4 + i;
                if (r < M) {
                    float v = acc[rs][t][i] * rsc[rs][i] + bv;
                    if (mode == 1) v = (v > 0.f) ? v : av * v;
                    if (mode == 2) Cf[(size_t)r * 128 + gcol] = v;
                    else           Cb[(size_t)r * 128 + gcol] = f2bf(v);
                }
            }
        }
    }
}

// ---------------- GCN aggregation: 32-lane group per node (2 nodes/wave), 4 feats/lane ----------------
// Hs rows PRE-SCALED by dinv[row]: out[n] = relu( dinv[n]*(sum_e Hs[src_e] + Hs[n]) + b )
__global__ __launch_bounds__(256) void aggregate(
    const unsigned short* __restrict__ Hs, const float* __restrict__ dinv,
    const int* __restrict__ rowptr, const int* __restrict__ epack,
    const float* __restrict__ bias, float* __restrict__ outF,
    unsigned short* __restrict__ outHi, int N)
{
    const int tid = threadIdx.x;
    const int g = tid >> 5;                 // 8 groups of 32 lanes
    const int l = tid & 31;
    const int n = blockIdx.x * 8 + g;
    if (n >= N) return;

    const int beg = rowptr[n], end = rowptr[n + 1];
    const size_t fo = (size_t)l * 4;        // this lane's 4-feature slot

    f32x4 a0 = {0.f, 0.f, 0.f, 0.f};
    f32x4 a1 = a0, a2 = a0, a3 = a0;

    int i = beg;
    for (; i + 3 < end; i += 4) {
        int s0 = epack[i];
        int s1 = epack[i + 1];
        int s2 = epack[i + 2];
        int s3 = epack[i + 3];
        us4 h0 = *(const us4*)(Hs + (size_t)s0 * 128 + fo);
        us4 h1 = *(const us4*)(Hs + (size_t)s1 * 128 + fo);
        us4 h2 = *(const us4*)(Hs + (size_t)s2 * 128 + fo);
        us4 h3 = *(const us4*)(Hs + (size_t)s3 * 128 + fo);
#pragma unroll
        for (int j = 0; j < 4; ++j) a0[j] += bf2f(h0[j]);
#pragma unroll
        for (int j = 0; j < 4; ++j) a1[j] += bf2f(h1[j]);
#pragma unroll
        for (int j = 0; j < 4; ++j) a2[j] += bf2f(h2[j]);
#pragma unroll
        for (int j = 0; j < 4; ++j) a3[j] += bf2f(h3[j]);
    }
    for (; i < end; ++i) {
        int s0 = epack[i];
        us4 h0 = *(const us4*)(Hs + (size_t)s0 * 128 + fo);
#pragma unroll
        for (int j = 0; j < 4; ++j) a0[j] += bf2f(h0[j]);
    }

    // self (pre-scaled) + normalize + bias + relu
    us4 sh = *(const us4*)(Hs + (size_t)n * 128 + fo);
    float dn = dinv[n];
    f32x4 b4 = *(const f32x4*)(bias + l * 4);
    f32x4 sum = (a0 + a1) + (a2 + a3);
    f32x4 v;
    us4 ob;
#pragma unroll
    for (int j = 0; j < 4; ++j) {
        v[j] = fmaxf(dn * (sum[j] + bf2f(sh[j])) + b4[j], 0.f);
        ob[j] = f2bf(v[j]);
    }
    if (outF) *(f32x4*)(outF + (size_t)n * 128 + fo) = v;
    *(us4*)(outHi + (size_t)n * 128 + fo) = ob;
}

// ---------------- launch ----------------
extern "C" void kernel_launch(void* const* d_in, const int* in_sizes, int n_in,
                              void* d_out, int out_size, void* d_ws, size_t ws_size,
                              hipStream_t stream)
{
    const float* x   = (const float*)d_in[0];
    const int*   ei  = (const int*)d_in[1];
    const float* W1  = (const float*)d_in[2];
    const float* b1  = (const float*)d_in[3];
    const float* W2  = (const float*)d_in[4];
    const float* b2  = (const float*)d_in[5];
    const float* Wp1 = (const float*)d_in[6];
    const float* bp1 = (const float*)d_in[7];
    const float* pa  = (const float*)d_in[8];
    const float* Wp2 = (const float*)d_in[9];
    const float* bp2 = (const float*)d_in[10];

    const int N = in_sizes[0] / 128;
    const int E = in_sizes[1] / 2;
    const int* src = ei;
    const int* dst = ei + E;

    float* outF = (float*)d_out;
    float* zbuf = outF;                        // output 0: z
    float* pbuf = outF + (size_t)N * 128;      // output 1: p

    char* w = (char*)d_ws;
    size_t off = 0;
    auto alloc = [&](size_t bytes) {
        void* p = w + off;
        off = (off + bytes + 255) & ~(size_t)255;
        return p;
    };
    unsigned short* S1 = (unsigned short*)alloc((size_t)N * 128 * sizeof(unsigned short));
    unsigned short* S2 = (unsigned short*)alloc((size_t)N * 128 * sizeof(unsigned short));
    float* dinv   = (float*)alloc((size_t)N * sizeof(float));
    int*   rowptr = (int*)alloc((size_t)(N + 1) * sizeof(int));
    int*   cntcur = (int*)alloc((size_t)N * sizeof(int));
    int*   epack  = (int*)alloc((size_t)E * sizeof(int));
    int*   bsum   = (int*)alloc(1024);
    unsigned short* wt = (unsigned short*)alloc((size_t)4 * 2 * 128 * 128 * sizeof(unsigned short));
    (void)ws_size; (void)n_in; (void)out_size;

    auto hiP = [&](int m) { return wt + (size_t)m * 32768; };
    auto loP = [&](int m) { return wt + (size_t)m * 32768 + 16384; };

    // weight conversion + cntcur zeroing (fused)
    hipLaunchKernelGGL(prep_w4, dim3(256), dim3(256), 0, stream, W1, W2, Wp1, Wp2, wt, cntcur, N);

    // CSR by dst
    const int nb = (N + 1023) >> 10;
    hipLaunchKernelGGL(count_deg, dim3((E + 255) / 256), dim3(256), 0, stream, dst, cntcur, E);
    hipLaunchKernelGGL(scanA,     dim3(nb), dim3(1024), 0, stream, cntcur, rowptr, bsum, N);
    hipLaunchKernelGGL(scanC,     dim3((N + 255) / 256), dim3(256), 0, stream, rowptr, bsum, cntcur, dinv, N, E);
    hipLaunchKernelGGL(fill_csr,  dim3(8 * ((E + 255) / 256)), dim3(256), 0, stream,
                       src, dst, cntcur, epack, E, N);

    const int gb = (N + 127) / 128;
    const int ab = (N + 7) / 8;
    // conv1: h1s = (x@W1)*dinv -> S2 (reads f32 x directly) ; z1 = relu(dinv*(agg+self)+b1) -> S1
    hipLaunchKernelGGL(gemm128s, dim3(gb), dim3(256), 0, stream,
                       (const unsigned short*)nullptr, x, hiP(0), loP(0),
                       (const float*)nullptr, (const float*)nullptr, dinv,
                       (float*)nullptr, S2, N, 0);
    hipLaunchKernelGGL(aggregate, dim3(ab), dim3(256), 0, stream, S2, dinv, rowptr, epack,
                       b1, (float*)nullptr, S1, N);
    // conv2: h2s = (z1@W2)*dinv -> S2 ; z = relu(dinv*(agg+self)+b2) -> zbuf(f32) + S1(bf16)
    hipLaunchKernelGGL(gemm128s, dim3(gb), dim3(256), 0, stream,
                       S1, (const float*)nullptr, hiP(1), loP(1),
                       (const float*)nullptr, (const float*)nullptr, dinv,
                       (float*)nullptr, S2, N, 0);
    hipLaunchKernelGGL(aggregate, dim3(ab), dim3(256), 0, stream, S2, dinv, rowptr, epack,
                       b2, zbuf, S1, N);
    // projection: h = prelu(z@Wp1+bp1) -> S2 ; p = h@Wp2+bp2 -> pbuf(f32)
    hipLaunchKernelGGL(gemm128s, dim3(gb), dim3(256), 0, stream,
                       S1, (const float*)nullptr, hiP(2), loP(2),
                       bp1, pa, (const float*)nullptr,
                       (float*)nullptr, S2, N, 1);
    hipLaunchKernelGGL(gemm128s, dim3(gb), dim3(256), 0, stream,
                       S2, (const float*)nullptr, hiP(3), loP(3),
                       bp2, (const float*)nullptr, (const float*)nullptr,
                       pbuf, (unsigned short*)nullptr, N, 2);
}

// Round 5
// 469.152 us; speedup vs baseline: 1.0434x; 1.0139x over previous
//
#include <hip/hip_runtime.h>

typedef __bf16 bf16x8 __attribute__((ext_vector_type(8)));
typedef float  f32x4  __attribute__((ext_vector_type(4)));
typedef unsigned short us8 __attribute__((ext_vector_type(8)));
typedef unsigned short us4 __attribute__((ext_vector_type(4)));

__device__ __forceinline__ float bf2f(unsigned short u) {
    return __builtin_bit_cast(float, (unsigned int)u << 16);
}
__device__ __forceinline__ unsigned short f2bf(float f) {
    return __builtin_bit_cast(unsigned short, (__bf16)f);
}

// ---------------- fused weight prep + cntcur zeroing ----------------
// wt layout per matrix m: [m*32768 .. ]: hiT[128*128], loT[128*128]
__global__ void prep_w4(const float* __restrict__ W0, const float* __restrict__ W1,
                        const float* __restrict__ W2, const float* __restrict__ W3,
                        unsigned short* __restrict__ wt, int* __restrict__ cnt, int N) {
    int i = blockIdx.x * 256 + threadIdx.x;    // 0..65535
    if (i < N) cnt[i] = 0;
    int i2 = i + 65536;
    if (i2 < N) cnt[i2] = 0;
    int m = i >> 14, r = i & 16383;
    const float* W = (m == 0) ? W0 : (m == 1) ? W1 : (m == 2) ? W2 : W3;
    float f = W[r];
    int k = r >> 7, n = r & 127;
    __bf16 h = (__bf16)f;
    __bf16 l = (__bf16)(f - (float)h);
    unsigned short* base = wt + m * 32768;
    base[n * 128 + k]         = __builtin_bit_cast(unsigned short, h);
    base[16384 + n * 128 + k] = __builtin_bit_cast(unsigned short, l);
}

// ---------------- CSR build ----------------
__global__ void count_deg(const int* __restrict__ dst, int* __restrict__ cnt, int E) {
    int e = blockIdx.x * 256 + threadIdx.x;
    if (e < E) atomicAdd(&cnt[dst[e]], 1);
}

// per-1024-block exclusive scan via wave shuffles
__global__ void scanA(const int* __restrict__ cnt, int* __restrict__ rowptr,
                      int* __restrict__ bsum, int N) {
    __shared__ int ws[16];
    int t = threadIdx.x;
    int idx = blockIdx.x * 1024 + t;
    int v = (idx < N) ? cnt[idx] : 0;
    int s = v;
#pragma unroll
    for (int o = 1; o < 64; o <<= 1) {
        int u = __shfl_up(s, o, 64);
        if ((t & 63) >= o) s += u;
    }
    int wid = t >> 6;
    if ((t & 63) == 63) ws[wid] = s;
    __syncthreads();
    if (t < 16) {
        int x = ws[t];
#pragma unroll
        for (int o = 1; o < 16; o <<= 1) {
            int u = __shfl_up(x, o, 64);
            if (t >= o) x += u;
        }
        ws[t] = x;
    }
    __syncthreads();
    int base = (wid > 0) ? ws[wid - 1] : 0;
    int inc = base + s;
    if (idx < N) rowptr[idx] = inc - v;       // exclusive
    if (t == 1023) bsum[blockIdx.x] = inc;    // block total
}

// finalize: per-block prefix of bsum computed in-block (nb <= 98 < 256)
__global__ void scanC(int* __restrict__ rowptr, const int* __restrict__ bsum,
                      int* __restrict__ cursor, float* __restrict__ dinv,
                      int N, int E) {
    __shared__ int wsum[4];
    __shared__ int sprefix;
    const int b = blockIdx.x;
    const int t = threadIdx.x;
    const int q = (b * 256) >> 10;
    int v = (t < q) ? bsum[t] : 0;
#pragma unroll
    for (int o = 32; o; o >>= 1) v += __shfl_down(v, o, 64);
    if ((t & 63) == 0) wsum[t >> 6] = v;
    __syncthreads();
    if (t == 0) sprefix = wsum[0] + wsum[1] + wsum[2] + wsum[3];
    __syncthreads();
    int i = b * 256 + t;
    if (i < N) {
        int c = cursor[i];
        int a = rowptr[i] + sprefix;
        rowptr[i] = a;
        cursor[i] = a;
        dinv[i] = rsqrtf((float)(c + 1));
    }
    if (i == 0) rowptr[N] = E;
}

// fill edge records (4B: src only), dst-range-partitioned so each range's
// scattered writes stay within ONE XCD's L2 and merge into full lines.
__global__ void fill_csr(const int* __restrict__ src, const int* __restrict__ dst,
                         int* __restrict__ cursor, int* __restrict__ epack,
                         int E, int N) {
    const int range = blockIdx.x & 7;
    const int e = (blockIdx.x >> 3) * 256 + threadIdx.x;
    const int RANGE = (N + 7) >> 3;
    const int lo = range * RANGE;
    const int hi = (lo + RANGE < N) ? lo + RANGE : N;
    if (e < E) {
        int d = dst[e];
        if (d >= lo && d < hi) {
            int p = atomicAdd(&cursor[d], 1);
            epack[p] = src[e];
        }
    }
}

// ---------------- GEMM: C[M,128] = A[M,128](bf16 or f32) @ W[128,128](split hi/lo) ----------------
// 512 threads, 8 waves tiled 2(row)x4(col): wave = 64 rows x 32 cols.
// Cuts per-block LDS b128 reads 2x vs 4x32-row waves (B shared across 4 row-slots)
// and doubles waves/SIMD (latency hiding); A re-reads stay L1-resident.
// Af32 != null : read f32 A, convert in-register (fused x->bf16)
// rowscale != null : C row r scaled by rowscale[r] before store
// mode 0: no bias, write Cb (bf16); mode 1: +bias, PReLU, write Cb; mode 2: +bias, write Cf (f32)
__global__ __launch_bounds__(512) void gemm128s(
    const unsigned short* __restrict__ Ahi, const float* __restrict__ Af32,
    const unsigned short* __restrict__ WhiT, const unsigned short* __restrict__ WloT,
    const float* __restrict__ bias, const float* __restrict__ prelu_a,
    const float* __restrict__ rowscale,
    float* __restrict__ Cf, unsigned short* __restrict__ Cb, int M, int mode)
{
    __shared__ unsigned short sHi[128 * 132];
    __shared__ unsigned short sLo[128 * 132];
    const int tid = threadIdx.x;

    for (int i = tid; i < 2048; i += 512) {
        int row = i >> 4, seg = i & 15;
        *(us8*)(&sHi[row * 132 + seg * 8]) = *(const us8*)(WhiT + row * 128 + seg * 8);
        *(us8*)(&sLo[row * 132 + seg * 8]) = *(const us8*)(WloT + row * 128 + seg * 8);
    }
    __syncthreads();

    const int lane = tid & 63;
    const int wave = tid >> 6;          // 0..7
    const int wr   = wave >> 2;         // 0..1 : 64-row half
    const int wc   = wave & 3;          // 0..3 : 32-col quarter
    const int lc   = lane & 15;
    const int quad = lane >> 4;
    const int rowBase = blockIdx.x * 128 + wr * 64;

    f32x4 acc[4][2];
    const f32x4 z4 = {0.f, 0.f, 0.f, 0.f};
#pragma unroll
    for (int rs = 0; rs < 4; ++rs)
#pragma unroll
        for (int tt = 0; tt < 2; ++tt) acc[rs][tt] = z4;

#pragma unroll
    for (int ks = 0; ks < 4; ++ks) {
        const int kf = ks * 32 + quad * 8;
        bf16x8 a[4];
#pragma unroll
        for (int rs = 0; rs < 4; ++rs) {
            int r = rowBase + rs * 16 + lc;
            if (r > M - 1) r = M - 1;
            if (Af32) {
                f32x4 p0 = *(const f32x4*)(Af32 + (size_t)r * 128 + kf);
                f32x4 p1 = *(const f32x4*)(Af32 + (size_t)r * 128 + kf + 4);
                us8 u;
#pragma unroll
                for (int j = 0; j < 4; ++j) { u[j] = f2bf(p0[j]); u[j + 4] = f2bf(p1[j]); }
                a[rs] = __builtin_bit_cast(bf16x8, u);
            } else {
                a[rs] = __builtin_bit_cast(bf16x8, *(const us8*)(Ahi + (size_t)r * 128 + kf));
            }
        }
#pragma unroll
        for (int tt = 0; tt < 2; ++tt) {
            const int trow = (wc * 2 + tt) * 16 + lc;
            bf16x8 bhi = __builtin_bit_cast(bf16x8, *(const us8*)(&sHi[trow * 132 + kf]));
            bf16x8 blo = __builtin_bit_cast(bf16x8, *(const us8*)(&sLo[trow * 132 + kf]));
#pragma unroll
            for (int rs = 0; rs < 4; ++rs) {
                acc[rs][tt] = __builtin_amdgcn_mfma_f32_16x16x32_bf16(a[rs], bhi, acc[rs][tt], 0, 0, 0);
                acc[rs][tt] = __builtin_amdgcn_mfma_f32_16x16x32_bf16(a[rs], blo, acc[rs][tt], 0, 0, 0);
            }
        }
    }

    float rsc[4][4];
#pragma unroll
    for (int rs = 0; rs < 4; ++rs)
#pragma unroll
        for (int i = 0; i < 4; ++i) {
            int r = rowBase + rs * 16 + quad * 4 + i;
            rsc[rs][i] = (rowscale && r < M) ? rowscale[r] : 1.f;
        }

    float av = (mode == 1) ? prelu_a[0] : 0.f;
#pragma unroll
    for (int tt = 0; tt < 2; ++tt) {
        int gcol = (wc * 2 + tt) * 16 + lc;
        float bv = (mode != 0) ? bias[gcol] : 0.f;
#pragma unroll
        for (int rs = 0; rs < 4; ++rs) {
#pragma unroll
            for (int i = 0; i < 4; ++i) {
                int r = rowBase + rs * 16 + quad * 4 + i;
                if (r < M) {
                    float v = acc[rs][tt][i] * rsc[rs][i] + bv;
                    if (mode == 1) v = (v > 0.f) ? v : av * v;
                    if (mode == 2) Cf[(size_t)r * 128 + gcol] = v;
                    else           Cb[(size_t)r * 128 + gcol] = f2bf(v);
                }
            }
        }
    }
}

// ---------------- GCN aggregation: 32-lane group per node (2 nodes/wave), 4 feats/lane ----------------
// Hs rows PRE-SCALED by dinv[row]: out[n] = relu( dinv[n]*(sum_e Hs[src_e] + Hs[n]) + b )
// Edge indices read as ALIGNED int4 (1 VMEM instr / 4 edges); boundary slots predicated.
__global__ __launch_bounds__(256) void aggregate(
    const unsigned short* __restrict__ Hs, const float* __restrict__ dinv,
    const int* __restrict__ rowptr, const int* __restrict__ epack,
    const float* __restrict__ bias, float* __restrict__ outF,
    unsigned short* __restrict__ outHi, int N)
{
    const int tid = threadIdx.x;
    const int g = tid >> 5;                 // 8 groups of 32 lanes
    const int l = tid & 31;
    const int n = blockIdx.x * 8 + g;
    if (n >= N) return;

    const int beg = rowptr[n], end = rowptr[n + 1];
    const size_t fo = (size_t)l * 4;        // this lane's 4-feature slot

    // hoist self row / bias / dinv loads above the gather loop (latency overlap)
    us4 sh = *(const us4*)(Hs + (size_t)n * 128 + fo);
    f32x4 b4 = *(const f32x4*)(bias + l * 4);
    float dn = dinv[n];

    f32x4 a0 = {0.f, 0.f, 0.f, 0.f};
    f32x4 a1 = a0, a2 = a0, a3 = a0;

    for (int i = (beg & ~3); i < end; i += 4) {
        int4 e = *(const int4*)(epack + i);     // 16B-aligned; E%4==0 keeps it in-bounds
        if (i >= beg && i + 4 <= end) {
            us4 h0 = *(const us4*)(Hs + (size_t)e.x * 128 + fo);
            us4 h1 = *(const us4*)(Hs + (size_t)e.y * 128 + fo);
            us4 h2 = *(const us4*)(Hs + (size_t)e.z * 128 + fo);
            us4 h3 = *(const us4*)(Hs + (size_t)e.w * 128 + fo);
#pragma unroll
            for (int j = 0; j < 4; ++j) a0[j] += bf2f(h0[j]);
#pragma unroll
            for (int j = 0; j < 4; ++j) a1[j] += bf2f(h1[j]);
#pragma unroll
            for (int j = 0; j < 4; ++j) a2[j] += bf2f(h2[j]);
#pragma unroll
            for (int j = 0; j < 4; ++j) a3[j] += bf2f(h3[j]);
        } else {
            if (i >= beg && i < end) {
                us4 h0 = *(const us4*)(Hs + (size_t)e.x * 128 + fo);
#pragma unroll
                for (int j = 0; j < 4; ++j) a0[j] += bf2f(h0[j]);
            }
            if (i + 1 >= beg && i + 1 < end) {
                us4 h1 = *(const us4*)(Hs + (size_t)e.y * 128 + fo);
#pragma unroll
                for (int j = 0; j < 4; ++j) a1[j] += bf2f(h1[j]);
            }
            if (i + 2 >= beg && i + 2 < end) {
                us4 h2 = *(const us4*)(Hs + (size_t)e.z * 128 + fo);
#pragma unroll
                for (int j = 0; j < 4; ++j) a2[j] += bf2f(h2[j]);
            }
            if (i + 3 >= beg && i + 3 < end) {
                us4 h3 = *(const us4*)(Hs + (size_t)e.w * 128 + fo);
#pragma unroll
                for (int j = 0; j < 4; ++j) a3[j] += bf2f(h3[j]);
            }
        }
    }

    // self (pre-scaled) + normalize + bias + relu
    f32x4 sum = (a0 + a1) + (a2 + a3);
    f32x4 v;
    us4 ob;
#pragma unroll
    for (int j = 0; j < 4; ++j) {
        v[j] = fmaxf(dn * (sum[j] + bf2f(sh[j])) + b4[j], 0.f);
        ob[j] = f2bf(v[j]);
    }
    if (outF) *(f32x4*)(outF + (size_t)n * 128 + fo) = v;
    *(us4*)(outHi + (size_t)n * 128 + fo) = ob;
}

// ---------------- launch ----------------
extern "C" void kernel_launch(void* const* d_in, const int* in_sizes, int n_in,
                              void* d_out, int out_size, void* d_ws, size_t ws_size,
                              hipStream_t stream)
{
    const float* x   = (const float*)d_in[0];
    const int*   ei  = (const int*)d_in[1];
    const float* W1  = (const float*)d_in[2];
    const float* b1  = (const float*)d_in[3];
    const float* W2  = (const float*)d_in[4];
    const float* b2  = (const float*)d_in[5];
    const float* Wp1 = (const float*)d_in[6];
    const float* bp1 = (const float*)d_in[7];
    const float* pa  = (const float*)d_in[8];
    const float* Wp2 = (const float*)d_in[9];
    const float* bp2 = (const float*)d_in[10];

    const int N = in_sizes[0] / 128;
    const int E = in_sizes[1] / 2;
    const int* src = ei;
    const int* dst = ei + E;

    float* outF = (float*)d_out;
    float* zbuf = outF;                        // output 0: z
    float* pbuf = outF + (size_t)N * 128;      // output 1: p

    char* w = (char*)d_ws;
    size_t off = 0;
    auto alloc = [&](size_t bytes) {
        void* p = w + off;
        off = (off + bytes + 255) & ~(size_t)255;
        return p;
    };
    unsigned short* S1 = (unsigned short*)alloc((size_t)N * 128 * sizeof(unsigned short));
    unsigned short* S2 = (unsigned short*)alloc((size_t)N * 128 * sizeof(unsigned short));
    float* dinv   = (float*)alloc((size_t)N * sizeof(float));
    int*   rowptr = (int*)alloc((size_t)(N + 1) * sizeof(int));
    int*   cntcur = (int*)alloc((size_t)N * sizeof(int));
    int*   epack  = (int*)alloc((size_t)E * sizeof(int));
    int*   bsum   = (int*)alloc(1024);
    unsigned short* wt = (unsigned short*)alloc((size_t)4 * 2 * 128 * 128 * sizeof(unsigned short));
    (void)ws_size; (void)n_in; (void)out_size;

    auto hiP = [&](int m) { return wt + (size_t)m * 32768; };
    auto loP = [&](int m) { return wt + (size_t)m * 32768 + 16384; };

    // weight conversion + cntcur zeroing (fused)
    hipLaunchKernelGGL(prep_w4, dim3(256), dim3(256), 0, stream, W1, W2, Wp1, Wp2, wt, cntcur, N);

    // CSR by dst
    const int nb = (N + 1023) >> 10;
    hipLaunchKernelGGL(count_deg, dim3((E + 255) / 256), dim3(256), 0, stream, dst, cntcur, E);
    hipLaunchKernelGGL(scanA,     dim3(nb), dim3(1024), 0, stream, cntcur, rowptr, bsum, N);
    hipLaunchKernelGGL(scanC,     dim3((N + 255) / 256), dim3(256), 0, stream, rowptr, bsum, cntcur, dinv, N, E);
    hipLaunchKernelGGL(fill_csr,  dim3(8 * ((E + 255) / 256)), dim3(256), 0, stream,
                       src, dst, cntcur, epack, E, N);

    const int gb = (N + 127) / 128;
    const int ab = (N + 7) / 8;
    // conv1: h1s = (x@W1)*dinv -> S2 (reads f32 x directly) ; z1 = relu(dinv*(agg+self)+b1) -> S1
    hipLaunchKernelGGL(gemm128s, dim3(gb), dim3(512), 0, stream,
                       (const unsigned short*)nullptr, x, hiP(0), loP(0),
                       (const float*)nullptr, (const float*)nullptr, dinv,
                       (float*)nullptr, S2, N, 0);
    hipLaunchKernelGGL(aggregate, dim3(ab), dim3(256), 0, stream, S2, dinv, rowptr, epack,
                       b1, (float*)nullptr, S1, N);
    // conv2: h2s = (z1@W2)*dinv -> S2 ; z = relu(dinv*(agg+self)+b2) -> zbuf(f32) + S1(bf16)
    hipLaunchKernelGGL(gemm128s, dim3(gb), dim3(512), 0, stream,
                       S1, (const float*)nullptr, hiP(1), loP(1),
                       (const float*)nullptr, (const float*)nullptr, dinv,
                       (float*)nullptr, S2, N, 0);
    hipLaunchKernelGGL(aggregate, dim3(ab), dim3(256), 0, stream, S2, dinv, rowptr, epack,
                       b2, zbuf, S1, N);
    // projection: h = prelu(z@Wp1+bp1) -> S2 ; p = h@Wp2+bp2 -> pbuf(f32)
    hipLaunchKernelGGL(gemm128s, dim3(gb), dim3(512), 0, stream,
                       S1, (const float*)nullptr, hiP(2), loP(2),
                       bp1, pa, (const float*)nullptr,
                       (float*)nullptr, S2, N, 1);
    hipLaunchKernelGGL(gemm128s, dim3(gb), dim3(512), 0, stream,
                       S2, (const float*)nullptr, hiP(3), loP(3),
                       bp2, (const float*)nullptr, (const float*)nullptr,
                       pbuf, (unsigned short*)nullptr, N, 2);
}